// Round 1
// baseline (21465.663 us; speedup 1.0000x reference)
//
#include <hip/hip_runtime.h>
#include <hip/hip_bf16.h>
#include <math.h>

#define L_SEQ   2048
#define BATCH   4
#define DMODEL  512
#define NHEADS  8
#define DKH     64
#define DFF     2048
#define NLAYERS 4
#define NVOC    32000
#define NTOK    (L_SEQ*BATCH)   // 8192

typedef _Float16 half8  __attribute__((ext_vector_type(8)));
typedef _Float16 half4v __attribute__((ext_vector_type(4)));
typedef float    floatx4 __attribute__((ext_vector_type(4)));

#define MB ((size_t)1 << 20)

// ---------------------------------------------------------------------------
// fp32 -> f16 cast (vectorized 4/thread)
__global__ void cast_kernel(const float* __restrict__ src, _Float16* __restrict__ dst, int n) {
    int i = (blockIdx.x * blockDim.x + threadIdx.x) * 4;
    if (i >= n) return;
    float4 v = *(const float4*)(src + i);
    half4v h = { (_Float16)v.x, (_Float16)v.y, (_Float16)v.z, (_Float16)v.w };
    *(half4v*)(dst + i) = h;
}

// ---------------------------------------------------------------------------
// embedding * sqrt(D) + sinusoidal PE; writes fp32 residual stream + f16 copy
__global__ void embed_kernel(const int* __restrict__ tok, const float* __restrict__ emb,
                             float* __restrict__ x32, _Float16* __restrict__ x16) {
    int id  = blockIdx.x * 256 + threadIdx.x;      // 0 .. NTOK*DMODEL
    int d   = id & (DMODEL - 1);
    int row = id >> 9;                             // l*BATCH + b
    int l   = row >> 2;
    float v = emb[(size_t)tok[row] * DMODEL + d] * 22.62741699796952f;  // sqrt(512)
    int i2 = d >> 1;
    float freq = expf((float)(2 * i2) * (-0.017988946039015984f));      // -ln(10000)/512
    float ang  = (float)l * freq;
    v += (d & 1) ? cosf(ang) : sinf(ang);
    x32[id] = v;
    x16[id] = (_Float16)v;
}

// ---------------------------------------------------------------------------
__device__ inline float wave_sum(float s) {
    s += __shfl_xor(s, 32); s += __shfl_xor(s, 16); s += __shfl_xor(s, 8);
    s += __shfl_xor(s, 4);  s += __shfl_xor(s, 2);  s += __shfl_xor(s, 1);
    return s;
}

// LayerNorm (torch-style: unbiased std, divide by (std + eps)).
// One wave per row of 512; writes fp32 + f16.
__global__ __launch_bounds__(256) void ln_kernel(const float* __restrict__ in,
                                                 const float* __restrict__ ga,
                                                 const float* __restrict__ be,
                                                 float* __restrict__ out32,
                                                 _Float16* __restrict__ out16) {
    int row  = (blockIdx.x * 256 + threadIdx.x) >> 6;
    int lane = threadIdx.x & 63;
    const float* p = in + (size_t)row * DMODEL;
    float vals[8];
    float s = 0.f;
#pragma unroll
    for (int j = 0; j < 8; ++j) { vals[j] = p[lane + 64 * j]; s += vals[j]; }
    s = wave_sum(s);
    float mean = s * (1.f / DMODEL);
    float s2 = 0.f;
#pragma unroll
    for (int j = 0; j < 8; ++j) { float dv = vals[j] - mean; s2 += dv * dv; }
    s2 = wave_sum(s2);
    float stdv = sqrtf(s2 * (1.f / (DMODEL - 1)));
    float inv  = 1.f / (stdv + 1e-6f);
#pragma unroll
    for (int j = 0; j < 8; ++j) {
        int d = lane + 64 * j;
        float y = (vals[j] - mean) * inv * ga[d] + be[d];
        out32[(size_t)row * DMODEL + d] = y;
        out16[(size_t)row * DMODEL + d] = (_Float16)y;
    }
}

// ---------------------------------------------------------------------------
// Flash attention, fp32, one wave per (h,b,l) query row; lane = head dim.
// q,k,v are [NTOK, DMODEL] fp32 (row = l*B+b, col = h*64+d). Output f16.
__global__ __launch_bounds__(256) void attn_kernel(const float* __restrict__ q,
                                                   const float* __restrict__ k,
                                                   const float* __restrict__ v,
                                                   _Float16* __restrict__ ctx16) {
    int wid  = (blockIdx.x * 256 + threadIdx.x) >> 6;
    int lane = threadIdx.x & 63;
    int l  = wid & (L_SEQ - 1);
    int hb = wid >> 11;
    int b  = hb & 3;
    int h  = hb >> 2;
    size_t qoff = ((size_t)(l * BATCH + b)) * DMODEL + h * DKH + lane;
    float qd = q[qoff] * 0.125f;          // 1/sqrt(DK)
    const float* kb = k + h * DKH + b * DMODEL + lane;
    const float* vb = v + h * DKH + b * DMODEL + lane;
    float m_run = -1e30f, l_run = 0.f, o = 0.f;
    for (int m = 0; m <= l; ++m) {
        float kv = kb[(size_t)m * (BATCH * DMODEL)];
        float vv = vb[(size_t)m * (BATCH * DMODEL)];
        float s = wave_sum(qd * kv);
        float mn = fmaxf(m_run, s);
        float alpha = __expf(m_run - mn);
        float p = __expf(s - mn);
        l_run = l_run * alpha + p;
        o = o * alpha + p * vv;
        m_run = mn;
    }
    ctx16[qoff] = (_Float16)(o / l_run);
}

// ---------------------------------------------------------------------------
// MFMA GEMM: C[M,N] = A[M,K] * B[N,K]^T (+bias[n]) (+res) (ReLU) ; f16 in, fp32 acc
// 128x128 tile, BK=32, 256 threads = 4 waves, each wave 64x64 (4x4 MFMA 16x16x32)
template<bool F32OUT, bool F16OUT, bool BIAS, bool RES, bool RELU>
__global__ __launch_bounds__(256) void gemm_kernel(
    const _Float16* __restrict__ A, const _Float16* __restrict__ B,
    float* __restrict__ C, _Float16* __restrict__ C16,
    const float* __restrict__ bias, const float* __restrict__ res,
    int M, int N, int K)
{
    __shared__ __align__(16) _Float16 As[128 * 32];
    __shared__ __align__(16) _Float16 Bs[128 * 32];
    const int tid  = threadIdx.x;
    const int wave = tid >> 6, lane = tid & 63;
    const int m0 = blockIdx.y * 128, n0 = blockIdx.x * 128;
    const int wr = (wave >> 1) * 64, wc = (wave & 1) * 64;
    const int r0 = tid >> 2, c0 = (tid & 3) * 8;      // staging: 16B chunk per thread
    const int lrow = lane & 15, lk = (lane >> 4) * 8; // fragment lane mapping

    floatx4 acc[4][4] = {};

    for (int k0 = 0; k0 < K; k0 += 32) {
        uint4 a0 = *(const uint4*)(A + (size_t)(m0 + r0)      * K + k0 + c0);
        uint4 a1 = *(const uint4*)(A + (size_t)(m0 + 64 + r0) * K + k0 + c0);
        uint4 b0 = *(const uint4*)(B + (size_t)(n0 + r0)      * K + k0 + c0);
        uint4 b1 = *(const uint4*)(B + (size_t)(n0 + 64 + r0) * K + k0 + c0);
        __syncthreads();
        *(uint4*)(As + r0 * 32 + c0)        = a0;
        *(uint4*)(As + (64 + r0) * 32 + c0) = a1;
        *(uint4*)(Bs + r0 * 32 + c0)        = b0;
        *(uint4*)(Bs + (64 + r0) * 32 + c0) = b1;
        __syncthreads();
        half8 af[4], bf[4];
#pragma unroll
        for (int i = 0; i < 4; ++i)
            af[i] = *(const half8*)(As + (wr + i * 16 + lrow) * 32 + lk);
#pragma unroll
        for (int i = 0; i < 4; ++i)
            bf[i] = *(const half8*)(Bs + (wc + i * 16 + lrow) * 32 + lk);
#pragma unroll
        for (int mi = 0; mi < 4; ++mi)
#pragma unroll
            for (int ni = 0; ni < 4; ++ni)
                acc[mi][ni] = __builtin_amdgcn_mfma_f32_16x16x32_f16(af[mi], bf[ni], acc[mi][ni], 0, 0, 0);
    }

    const int crow = (lane >> 4) * 4;   // + reg i
    const int ccol = lane & 15;
#pragma unroll
    for (int mi = 0; mi < 4; ++mi) {
#pragma unroll
        for (int ni = 0; ni < 4; ++ni) {
            int col = n0 + wc + ni * 16 + ccol;
            float bv = BIAS ? bias[col] : 0.f;
#pragma unroll
            for (int i = 0; i < 4; ++i) {
                int row = m0 + wr + mi * 16 + crow + i;
                float val = acc[mi][ni][i] + bv;
                if (RES)  val += res[(size_t)row * N + col];
                if (RELU) val = fmaxf(val, 0.f);
                if (F32OUT) C[(size_t)row * N + col] = val;
                if (F16OUT) C16[(size_t)row * N + col] = (_Float16)val;
            }
        }
    }
}

// ---------------------------------------------------------------------------
extern "C" void kernel_launch(void* const* d_in, const int* in_sizes, int n_in,
                              void* d_out, int out_size, void* d_ws, size_t ws_size,
                              hipStream_t stream) {
    const int*   tok  = (const int*)  d_in[0];
    const float* emb  = (const float*)d_in[1];
    const float* Wq   = (const float*)d_in[2];
    const float* Wk   = (const float*)d_in[3];
    const float* Wv   = (const float*)d_in[4];
    const float* Wo   = (const float*)d_in[5];
    const float* w1   = (const float*)d_in[6];
    const float* b1   = (const float*)d_in[7];
    const float* w2   = (const float*)d_in[8];
    const float* b2   = (const float*)d_in[9];
    const float* ln1a = (const float*)d_in[10];
    const float* ln1b = (const float*)d_in[11];
    const float* ln2a = (const float*)d_in[12];
    const float* ln2b = (const float*)d_in[13];
    const float* fna  = (const float*)d_in[14];
    const float* fnb  = (const float*)d_in[15];
    const float* decW = (const float*)d_in[16];
    const float* decb = (const float*)d_in[17];

    // d_out (1000 MiB) doubles as activation scratch; fully overwritten by the
    // final decoder GEMM, which reads only from d_ws.
    char* o = (char*)d_out;
    float*    x32    = (float*)(o + 0 * MB);
    float*    h32    = (float*)(o + 16 * MB);
    float*    q      = (float*)(o + 32 * MB);
    float*    k      = (float*)(o + 48 * MB);
    float*    v      = (float*)(o + 64 * MB);
    _Float16* ctx16  = (_Float16*)(o + 80 * MB);
    _Float16* wq16   = (_Float16*)(o + 88 * MB);
    _Float16* wk16   = (_Float16*)(o + 90 * MB);
    _Float16* wv16   = (_Float16*)(o + 92 * MB);
    _Float16* wo16   = (_Float16*)(o + 94 * MB);
    _Float16* w116   = (_Float16*)(o + 96 * MB);
    _Float16* w216   = (_Float16*)(o + 104 * MB);
    _Float16* f16buf = (_Float16*)(o + 112 * MB);   // ends at 144 MiB

    char* w = (char*)d_ws;                 // needs ~41 MiB
    _Float16* x16  = (_Float16*)(w);              // 8 MiB
    _Float16* dw16 = (_Float16*)(w + 8 * MB);     // 32.8 MiB

    auto cast = [&](const float* s, _Float16* d, int n) {
        cast_kernel<<<(n / 4 + 255) / 256, 256, 0, stream>>>(s, d, n);
    };
    cast(Wq, wq16, NLAYERS * DMODEL * DMODEL);
    cast(Wk, wk16, NLAYERS * DMODEL * DMODEL);
    cast(Wv, wv16, NLAYERS * DMODEL * DMODEL);
    cast(Wo, wo16, NLAYERS * DMODEL * DMODEL);
    cast(w1, w116, NLAYERS * DFF * DMODEL);
    cast(w2, w216, NLAYERS * DMODEL * DFF);
    cast(decW, dw16, NVOC * DMODEL);

    embed_kernel<<<NTOK * DMODEL / 256, 256, 0, stream>>>(tok, emb, x32, x16);

    dim3 blk(256);
    dim3 g512(DMODEL / 128, NTOK / 128);   // (4, 64)
    dim3 gff(DFF / 128, NTOK / 128);       // (16, 64)
    dim3 gdec(NVOC / 128, NTOK / 128);     // (250, 64)

    for (int i = 0; i < NLAYERS; ++i) {
        const _Float16* wqL = wq16 + (size_t)i * DMODEL * DMODEL;
        const _Float16* wkL = wk16 + (size_t)i * DMODEL * DMODEL;
        const _Float16* wvL = wv16 + (size_t)i * DMODEL * DMODEL;
        const _Float16* woL = wo16 + (size_t)i * DMODEL * DMODEL;
        const _Float16* w1L = w116 + (size_t)i * DFF * DMODEL;
        const _Float16* w2L = w216 + (size_t)i * DMODEL * DFF;

        gemm_kernel<1,0,0,0,0><<<g512, blk, 0, stream>>>(x16, wqL, q, nullptr, nullptr, nullptr, NTOK, DMODEL, DMODEL);
        gemm_kernel<1,0,0,0,0><<<g512, blk, 0, stream>>>(x16, wkL, k, nullptr, nullptr, nullptr, NTOK, DMODEL, DMODEL);
        gemm_kernel<1,0,0,0,0><<<g512, blk, 0, stream>>>(x16, wvL, v, nullptr, nullptr, nullptr, NTOK, DMODEL, DMODEL);

        attn_kernel<<<NTOK * NHEADS / 4, blk, 0, stream>>>(q, k, v, ctx16);

        // h = x + ctx @ Wo^T
        gemm_kernel<1,0,0,1,0><<<g512, blk, 0, stream>>>(ctx16, woL, h32, nullptr, nullptr, x32, NTOK, DMODEL, DMODEL);
        ln_kernel<<<NTOK / 4, blk, 0, stream>>>(h32, ln1a + i * DMODEL, ln1b + i * DMODEL, x32, x16);

        // f = relu(x @ w1^T + b1)  (f16 only)
        gemm_kernel<0,1,1,0,1><<<gff, blk, 0, stream>>>(x16, w1L, nullptr, f16buf, b1 + i * DFF, nullptr, NTOK, DFF, DMODEL);
        // h = x + f @ w2^T + b2
        gemm_kernel<1,0,1,1,0><<<g512, blk, 0, stream>>>(f16buf, w2L, h32, nullptr, b2 + i * DMODEL, x32, NTOK, DMODEL, DFF);
        ln_kernel<<<NTOK / 4, blk, 0, stream>>>(h32, ln2a + i * DMODEL, ln2b + i * DMODEL, x32, x16);
    }

    ln_kernel<<<NTOK / 4, blk, 0, stream>>>(x32, fna, fnb, x32, x16);

    // logits = x @ dec_W^T + dec_b   (overwrites all of d_out)
    gemm_kernel<1,0,1,0,0><<<gdec, blk, 0, stream>>>(x16, dw16, (float*)d_out, nullptr, decb, nullptr, NTOK, NVOC, DMODEL);
}